// Round 3
// baseline (277.567 us; speedup 1.0000x reference)
//
#include <hip/hip_runtime.h>
#include <hip/hip_bf16.h>

#define T_TOTAL 200000
#define BATCH 256
#define NBIT 64
#define NCLASS 100
#define TN 128
#define NBLK ((T_TOTAL + TN - 1) / TN)   // 1563

typedef __attribute__((ext_vector_type(8))) short bf16x8;
typedef __attribute__((ext_vector_type(4))) float f32x4;

#define LOG2E 1.4426950408889634f
#define LN2   0.6931471805599453

__device__ __forceinline__ float sgnf(float v) {
    return (v > 0.f) ? 1.f : ((v < 0.f) ? -1.f : 0.f);
}

__device__ __forceinline__ unsigned int pk2(float a, float b) {
    union { __hip_bfloat162 h2; unsigned int ui; } cv;
    cv.h2 = __float22bfloat162_rn(make_float2(a, b));   // low short = a (RNE)
    return cv.ui;
}

// ---------------- kernel A: batch labels + prescaled bf16 A-fragments --------
__global__ __launch_bounds__(256) void prep_kernel(const float* __restrict__ u,
                                                   const float* __restrict__ y,
                                                   int* __restrict__ labB,
                                                   unsigned short* __restrict__ Abf) {
    const int gt = blockIdx.x * 256 + threadIdx.x;      // 0..2047
    // Abf[j][k] = bf16(0.5*u[j][k]) : 4096 float4s of u, 2 per thread
    {
        const int f = gt * 2;                            // even -> same row, consecutive
        const int row = f >> 4, p = f & 15;
        const float4* up = reinterpret_cast<const float4*>(u);
        float4 a = up[f], b = up[f + 1];
        uint4 w = make_uint4(pk2(0.5f * a.x, 0.5f * a.y), pk2(0.5f * a.z, 0.5f * a.w),
                             pk2(0.5f * b.x, 0.5f * b.y), pk2(0.5f * b.z, 0.5f * b.w));
        *reinterpret_cast<uint4*>(&Abf[row * 64 + p * 4]) = w;
    }
    if (gt < BATCH) {
        const float4* yp = reinterpret_cast<const float4*>(y + gt * NCLASS); // 400B-aligned
        int l = 0;
        #pragma unroll
        for (int p = 0; p < 25; ++p) {
            float4 v = yp[p];
            if (v.x > 0.5f) l = p * 4;
            if (v.y > 0.5f) l = p * 4 + 1;
            if (v.z > 0.5f) l = p * 4 + 2;
            if (v.w > 0.5f) l = p * 4 + 3;
        }
        labB[gt] = l;
    }
}

// ---------------- kernel B: buffer label extraction (streaming) --------------
__global__ __launch_bounds__(256) void laby_kernel(const float* __restrict__ Y,
                                                   int* __restrict__ lab_buf) {
    const unsigned stride = gridDim.x * 256;
    const float4* Y4 = reinterpret_cast<const float4*>(Y);
    for (unsigned q = blockIdx.x * 256 + threadIdx.x; q < 5000000u; q += stride) {
        float4 v = Y4[q];
        unsigned r = q / 50000u;                 // row (0..99); 200000%4==0: no row crossing
        unsigned t = (q - r * 50000u) * 4u;
        if (v.x > 0.5f) lab_buf[t]     = (int)r;  // exactly one writer per column
        if (v.y > 0.5f) lab_buf[t + 1] = (int)r;
        if (v.z > 0.5f) lab_buf[t + 2] = (int)r;
        if (v.w > 0.5f) lab_buf[t + 3] = (int)r;
    }
}

// ---------------- kernel C: DCC center update + quantization loss ------------
__global__ __launch_bounds__(256) void dcc_kernel(const float* __restrict__ u,
                                                  const float* __restrict__ C,
                                                  const int* __restrict__ lab,
                                                  float* __restrict__ out_c,   // d_out+1
                                                  float* __restrict__ quant_out) {
    __shared__ float Q[NCLASS][NBIT];    // 25.6 KB
    __shared__ float Ct[NCLASS][NBIT];   // 25.6 KB (holds ORIGINAL C until phase 2)
    __shared__ int   labL[BATCH];
    __shared__ float wq[4];

    const int tid = threadIdx.x;
    const int k   = tid & 63;
    const int g   = tid >> 6;            // 0..3 (wave id)

    labL[tid] = lab[tid];
    for (int o = tid; o < NCLASS * NBIT; o += 256) {
        ((float*)Q)[o] = 0.f;
        int i = o >> 6, kk = o & 63;                 // o = i*64 + kk
        Ct[i][kk] = C[kk * NCLASS + i];
    }
    __syncthreads();

    // Q[i][k] = sum_{j: lab_j==i} b[k][j];  quant = sum (b - u)^2
    float qloc = 0.f;
    for (int jj = 0; jj < 64; ++jj) {
        int j = g * 64 + jj;
        int lj = labL[j];                            // wave-uniform broadcast
        float uu = u[j * NBIT + k];
        float b = sgnf(Ct[lj][k] + uu);              // MU = 1; Ct == original C here
        atomicAdd(&Q[lj][k], b);                     // exact small ints: order-independent
        float d = b - uu;
        qloc += d * d;
    }
    for (int off = 32; off; off >>= 1) qloc += __shfl_xor(qloc, off);
    if ((tid & 63) == 0) wq[g] = qloc;
    __syncthreads();
    if (tid == 0) quant_out[0] = wq[0] + wq[1] + wq[2] + wq[3];

    // sequential cyclic coordinate descent (wave 0 only); G off-diag == 0 (one-hot)
    if (tid < 64) {
        float total = 0.f;
        for (int i = 0; i < NCLASS; ++i) total += Ct[i][k];
        for (int i = 0; i < NCLASS; ++i) {
            float old = Ct[i][k];
            float v = Q[i][k] - (total - old);       // VUL = 1
            float nr = sgnf(v);                      // exact: can be 0.0
            Ct[i][k] = nr;
            total += nr - old;
        }
    }
    __syncthreads();
    // C_new[k][i] = Ct[i][k]
    for (int o = tid; o < NCLASS * NBIT; o += 256) {
        int kk = o / NCLASS, i = o - kk * NCLASS;
        out_c[o] = Ct[i][kk];
    }
}

// ---------------- kernel D: metric loss (bf16 MFMA, fused softplus) ----------
// LDS Bt: [col][64 k] shorts, 128B pitch, XOR-swizzled: short index = col*64 + (k0 ^ ((col&7)<<3)).
// All Bt accesses are 16B (k0 % 8 == 0) and use the same swizzle -> consistent & conflict-free.
__global__ __launch_bounds__(256, 6) void metric_kernel(const float* __restrict__ u,
                                                        const float* __restrict__ U,
                                                        const int* __restrict__ ind,
                                                        const int* __restrict__ labB_g,
                                                        const int* __restrict__ lab_buf,
                                                        const unsigned short* __restrict__ Abf,
                                                        double* __restrict__ partial) {
    __shared__ unsigned short Bt[TN * 64];   // 16 KB
    __shared__ int   labT[TN];
    __shared__ int   labB[BATCH];
    __shared__ float wpart[4];

    const int tid = threadIdx.x;
    const long t0 = (long)blockIdx.x * TN;

    labB[tid] = labB_g[tid];
    if (tid < TN) {
        long t = t0 + tid;
        labT[tid] = (t < (long)T_TOTAL) ? lab_buf[t] : -1;
    }

    // ---- stage U tile (bf16, transposed, swizzled) ----
    {
        const int c = tid & 127;
        const int h = tid >> 7;                     // 0..1 (wave-uniform)
        const long t = t0 + c;
        const bool ok = (t < (long)T_TOTAL);
        const int sw = (c & 7) << 3;
        #pragma unroll
        for (int m = 0; m < 4; ++m) {
            unsigned int w[4];
            #pragma unroll
            for (int pp = 0; pp < 4; ++pp) {
                const int kk = h * 32 + m * 8 + 2 * pp;
                float v0 = 0.f, v1 = 0.f;
                if (ok) {
                    v0 = U[(long)kk * T_TOTAL + t];
                    v1 = U[(long)(kk + 1) * T_TOTAL + t];
                }
                w[pp] = pk2(v0, v1);
            }
            const int k0 = h * 32 + m * 8;
            *reinterpret_cast<uint4*>(&Bt[c * 64 + (k0 ^ sw)]) = make_uint4(w[0], w[1], w[2], w[3]);
        }
    }
    __syncthreads();
    // ---- overwrite replaced columns (U_new / Y_new at ind; ind unique) ----
    {
        long c = (long)ind[tid] - t0;
        if (c >= 0 && c < TN) {
            labT[c] = labB[tid];
            const int ci = (int)c;
            const int sw = (ci & 7) << 3;
            #pragma unroll
            for (int m = 0; m < 8; ++m) {
                unsigned int w[4];
                #pragma unroll
                for (int pp = 0; pp < 4; ++pp) {
                    float v0 = u[tid * NBIT + m * 8 + 2 * pp];
                    float v1 = u[tid * NBIT + m * 8 + 2 * pp + 1];
                    w[pp] = pk2(v0, v1);
                }
                *reinterpret_cast<uint4*>(&Bt[ci * 64 + ((m * 8) ^ sw)]) = make_uint4(w[0], w[1], w[2], w[3]);
            }
        }
    }
    __syncthreads();

    // ---- A fragments: preconverted bf16(0.5*u), direct 16B loads ----
    const int wid  = tid >> 6;
    const int lane = tid & 63;
    const int lr   = lane & 15;
    const int g4   = lane >> 4;

    bf16x8 afrag[4][2];
    #pragma unroll
    for (int mt = 0; mt < 4; ++mt) {
        #pragma unroll
        for (int kb = 0; kb < 2; ++kb) {
            const int j = wid * 64 + mt * 16 + lr;
            union { bf16x8 v; uint4 q; } pk;
            pk.q = *reinterpret_cast<const uint4*>(&Abf[j * 64 + kb * 32 + g4 * 8]);
            afrag[mt][kb] = pk.v;
        }
    }
    int labR[4][4];
    #pragma unroll
    for (int mt = 0; mt < 4; ++mt)
        #pragma unroll
        for (int e = 0; e < 4; ++e)
            labR[mt][e] = labB[wid * 64 + mt * 16 + g4 * 4 + e];

    // ---- MFMA + fused softplus epilogue (ip pre-scaled by 0.5 via Abf) ----
    float sum2 = 0.f;
    for (int nt = 0; nt < 8; ++nt) {
        if (t0 + nt * 16 >= (long)T_TOTAL) break;   // block-uniform; 200000 % 16 == 0
        const int col = nt * 16 + lr;
        const int sw = (col & 7) << 3;
        union { bf16x8 v; uint4 q; } b0, b1;
        b0.q = *reinterpret_cast<const uint4*>(&Bt[col * 64 + ((g4 * 8) ^ sw)]);
        b1.q = *reinterpret_cast<const uint4*>(&Bt[col * 64 + ((32 + g4 * 8) ^ sw)]);
        const int labc = labT[col];
        #pragma unroll
        for (int mt = 0; mt < 4; ++mt) {
            f32x4 acc4 = {0.f, 0.f, 0.f, 0.f};
            acc4 = __builtin_amdgcn_mfma_f32_16x16x32_bf16(afrag[mt][0], b0.v, acc4, 0, 0, 0);
            acc4 = __builtin_amdgcn_mfma_f32_16x16x32_bf16(afrag[mt][1], b1.v, acc4, 0, 0, 0);
            #pragma unroll
            for (int e = 0; e < 4; ++e) {
                float ip = fminf(fmaxf(acc4[e], -100.f), 50.f);
                float z  = (labc == labR[mt][e]) ? -ip : ip;
                float tt = fmaf(z, LOG2E, LOG2E);    // (1+z)*log2(e), M = 1
                float e2 = exp2f(tt);
                sum2 += log2f(1.f + e2);             // * ln2 applied below
            }
        }
    }
    for (int off = 32; off; off >>= 1) sum2 += __shfl_xor(sum2, off);
    if (lane == 0) wpart[wid] = sum2;
    __syncthreads();
    if (tid == 0)
        partial[blockIdx.x] = (double)(wpart[0] + wpart[1] + wpart[2] + wpart[3]) * LN2;
}

// ---------------- kernel E: finalize loss ------------------------------------
__global__ __launch_bounds__(256) void fin_kernel(const double* __restrict__ partial,
                                                  const float* __restrict__ quant,
                                                  float* __restrict__ out0) {
    __shared__ double wp[4];
    double s = 0.0;
    for (int i = threadIdx.x; i < NBLK; i += 256) s += partial[i];
    for (int off = 32; off; off >>= 1) s += __shfl_xor(s, off);
    if ((threadIdx.x & 63) == 0) wp[threadIdx.x >> 6] = s;
    __syncthreads();
    if (threadIdx.x == 0) {
        double tot = wp[0] + wp[1] + wp[2] + wp[3];
        out0[0] = (float)(tot / ((double)BATCH * (double)T_TOTAL)
                          + 0.5 * ((double)quant[0] / (double)(BATCH * NBIT)));   // ETA=0.5
    }
}

extern "C" void kernel_launch(void* const* d_in, const int* in_sizes, int n_in,
                              void* d_out, int out_size, void* d_ws, size_t ws_size,
                              hipStream_t stream) {
    const float* u   = (const float*)d_in[0];
    const float* y   = (const float*)d_in[1];
    const int*   ind = (const int*)d_in[2];
    const float* U   = (const float*)d_in[3];
    const float* Y   = (const float*)d_in[4];
    const float* C   = (const float*)d_in[5];
    float* out = (float*)d_out;

    // ws layout (all write-before-read each call)
    float*          quant   = (float*)d_ws;                                   // 4 B
    int*            labB    = (int*)((char*)d_ws + 64);                       // 1 KB
    unsigned short* Abf     = (unsigned short*)((char*)d_ws + 2048);          // 32 KB
    double*         partial = (double*)((char*)d_ws + 36864);                 // 12.5 KB
    int*            lab_buf = (int*)((char*)d_ws + 65536);                    // 800 KB

    prep_kernel<<<8, 256, 0, stream>>>(u, y, labB, Abf);
    laby_kernel<<<2048, 256, 0, stream>>>(Y, lab_buf);
    dcc_kernel<<<1, 256, 0, stream>>>(u, C, labB, out + 1, quant);
    metric_kernel<<<NBLK, 256, 0, stream>>>(u, U, ind, labB, lab_buf, Abf, partial);
    fin_kernel<<<1, 256, 0, stream>>>(partial, quant, out);
}

// Round 4
// 271.836 us; speedup vs baseline: 1.0211x; 1.0211x over previous
//
#include <hip/hip_runtime.h>
#include <hip/hip_bf16.h>

#define T_TOTAL 200000
#define BATCH 256
#define NBIT 64
#define NCLASS 100
#define TN 128
#define NBLK ((T_TOTAL + TN - 1) / TN)   // 1563
#define YBLK 196                         // float4-blocks per Y row: 196*256 >= 50000

typedef __attribute__((ext_vector_type(8))) short bf16x8;
typedef __attribute__((ext_vector_type(4))) float f32x4;

#define LOG2E 1.4426950408889634f
#define LN2   0.6931471805599453

__device__ __forceinline__ float sgnf(float v) {
    return (v > 0.f) ? 1.f : ((v < 0.f) ? -1.f : 0.f);
}

__device__ __forceinline__ unsigned int pk2(float a, float b) {
    union { __hip_bfloat162 h2; unsigned int ui; } cv;
    cv.h2 = __float22bfloat162_rn(make_float2(a, b));   // low short = a (RNE)
    return cv.ui;
}

// raw HW transcendentals: v_exp_f32 = 2^x, v_log_f32 = log2(x)  (~1 ULP)
__device__ __forceinline__ float hw_exp2(float x) {
    float r; asm("v_exp_f32 %0, %1" : "=v"(r) : "v"(x)); return r;
}
__device__ __forceinline__ float hw_log2(float x) {
    float r; asm("v_log_f32 %0, %1" : "=v"(r) : "v"(x)); return r;
}

// ------- kernel A: buffer label extraction + (folded) batch labels & Abf -----
// grid: YBLK*NCLASS blocks of Y-scan work + 8 blocks of prep work
__global__ __launch_bounds__(256) void laby_prep_kernel(const float* __restrict__ Y,
                                                        int* __restrict__ lab_buf,
                                                        const float* __restrict__ u,
                                                        const float* __restrict__ y,
                                                        int* __restrict__ labB,
                                                        unsigned short* __restrict__ Abf) {
    const int bid = blockIdx.x;
    if (bid < YBLK * NCLASS) {
        const int row = bid / YBLK;                 // compile-time magic-div
        const int xb  = bid - row * YBLK;
        const int t4  = xb * 256 + threadIdx.x;     // float4 index within the row
        if (t4 < T_TOTAL / 4) {
            float4 v = reinterpret_cast<const float4*>(Y)[(long)row * (T_TOTAL / 4) + t4];
            const int t = t4 * 4;
            if (v.x > 0.5f) lab_buf[t]     = row;   // exactly one writer per column
            if (v.y > 0.5f) lab_buf[t + 1] = row;
            if (v.z > 0.5f) lab_buf[t + 2] = row;
            if (v.w > 0.5f) lab_buf[t + 3] = row;
        }
    } else {
        const int gt = (bid - YBLK * NCLASS) * 256 + threadIdx.x;   // 0..2047
        // Abf[j][k] = bf16(0.5*u[j][k]) : 4096 float4s of u, 2 per thread
        {
            const int f = gt * 2;
            const int row = f >> 4, p = f & 15;
            const float4* up = reinterpret_cast<const float4*>(u);
            float4 a = up[f], b = up[f + 1];
            uint4 w = make_uint4(pk2(0.5f * a.x, 0.5f * a.y), pk2(0.5f * a.z, 0.5f * a.w),
                                 pk2(0.5f * b.x, 0.5f * b.y), pk2(0.5f * b.z, 0.5f * b.w));
            *reinterpret_cast<uint4*>(&Abf[row * 64 + p * 4]) = w;
        }
        if (gt < BATCH) {
            const float4* yp = reinterpret_cast<const float4*>(y + gt * NCLASS);
            int l = 0;
            #pragma unroll
            for (int p = 0; p < 25; ++p) {
                float4 v = yp[p];
                if (v.x > 0.5f) l = p * 4;
                if (v.y > 0.5f) l = p * 4 + 1;
                if (v.z > 0.5f) l = p * 4 + 2;
                if (v.w > 0.5f) l = p * 4 + 3;
            }
            labB[gt] = l;
        }
    }
}

// ---------------- kernel B: DCC center update + quantization loss ------------
__global__ __launch_bounds__(256) void dcc_kernel(const float* __restrict__ u,
                                                  const float* __restrict__ C,
                                                  const int* __restrict__ lab,
                                                  float* __restrict__ out_c,   // d_out+1
                                                  float* __restrict__ quant_out) {
    __shared__ float Q[NCLASS][NBIT];        // 25.6 KB, [class][bit]
    __shared__ float Ct2[NBIT * NCLASS];     // 25.6 KB, [bit][class] == C layout
    __shared__ int   labL[BATCH];
    __shared__ float wq[4];

    const int tid = threadIdx.x;
    const int k   = tid & 63;
    const int g   = tid >> 6;                // 0..3 (wave id)

    labL[tid] = lab[tid];
    for (int o = tid; o < NCLASS * NBIT; o += 256) {
        ((float*)Q)[o] = 0.f;
        Ct2[o] = C[o];                       // coalesced global + LDS
    }
    __syncthreads();

    // Q[i][k] = sum_{j: lab_j==i} b[k][j];  quant = sum (b - u)^2
    float qloc = 0.f;
    for (int jj = 0; jj < 64; ++jj) {
        int j = g * 64 + jj;
        int lj = labL[j];                    // wave-uniform broadcast
        float uu = u[j * NBIT + k];
        float b = sgnf(Ct2[k * NCLASS + lj] + uu);   // MU = 1; original C
        atomicAdd(&Q[lj][k], b);             // exact small ints: order-independent
        float d = b - uu;
        qloc += d * d;
    }
    for (int off = 32; off; off >>= 1) qloc += __shfl_xor(qloc, off);
    if ((tid & 63) == 0) wq[g] = qloc;
    __syncthreads();
    if (tid == 0) quant_out[0] = wq[0] + wq[1] + wq[2] + wq[3];

    // sequential cyclic coordinate descent (wave 0); G off-diag == 0 (one-hot)
    if (tid < 64) {
        float total = 0.f;
        for (int i = 0; i < NCLASS; ++i) total += Ct2[k * NCLASS + i];
        float qn = Q[0][k], cn = Ct2[k * NCLASS];
        for (int i = 0; i < NCLASS; ++i) {
            float qc = qn, old = cn;
            if (i + 1 < NCLASS) { qn = Q[i + 1][k]; cn = Ct2[k * NCLASS + i + 1]; }
            float nr = sgnf(qc - (total - old));     // VUL = 1; exact, can be 0.0
            Ct2[k * NCLASS + i] = nr;
            total += nr - old;
        }
    }
    __syncthreads();
    // C_new is already in C's own layout: direct coalesced copy
    for (int o = tid; o < NCLASS * NBIT; o += 256) out_c[o] = Ct2[o];
}

// ---------------- kernel C: metric loss (bf16 MFMA, fused softplus) ----------
// LDS Bt: [col][64 k] shorts, 128B pitch, XOR-swizzled: short index = col*64 + (k0 ^ ((col&7)<<3)).
// All Bt accesses are 16B (k0 % 8 == 0) and use the same swizzle -> consistent & conflict-free.
__global__ __launch_bounds__(256, 6) void metric_kernel(const float* __restrict__ u,
                                                        const float* __restrict__ U,
                                                        const int* __restrict__ ind,
                                                        const int* __restrict__ labB_g,
                                                        const int* __restrict__ lab_buf,
                                                        const unsigned short* __restrict__ Abf,
                                                        double* __restrict__ partial) {
    __shared__ unsigned short Bt[TN * 64];   // 16 KB
    __shared__ int   labT[TN];
    __shared__ int   labB[BATCH];
    __shared__ float wpart[4];

    const int tid = threadIdx.x;
    const long t0 = (long)blockIdx.x * TN;

    labB[tid] = labB_g[tid];
    if (tid < TN) {
        long t = t0 + tid;
        labT[tid] = (t < (long)T_TOTAL) ? lab_buf[t] : -1;
    }

    // ---- stage U tile (bf16, transposed, swizzled) ----
    {
        const int c = tid & 127;
        const int h = tid >> 7;                     // 0..1 (wave-uniform)
        const long t = t0 + c;
        const bool ok = (t < (long)T_TOTAL);
        const int sw = (c & 7) << 3;
        #pragma unroll
        for (int m = 0; m < 4; ++m) {
            unsigned int w[4];
            #pragma unroll
            for (int pp = 0; pp < 4; ++pp) {
                const int kk = h * 32 + m * 8 + 2 * pp;
                float v0 = 0.f, v1 = 0.f;
                if (ok) {
                    v0 = U[(long)kk * T_TOTAL + t];
                    v1 = U[(long)(kk + 1) * T_TOTAL + t];
                }
                w[pp] = pk2(v0, v1);
            }
            const int k0 = h * 32 + m * 8;
            *reinterpret_cast<uint4*>(&Bt[c * 64 + (k0 ^ sw)]) = make_uint4(w[0], w[1], w[2], w[3]);
        }
    }
    __syncthreads();
    // ---- overwrite replaced columns (U_new / Y_new at ind; ind unique) ----
    {
        long c = (long)ind[tid] - t0;
        if (c >= 0 && c < TN) {
            labT[c] = labB[tid];
            const int ci = (int)c;
            const int sw = (ci & 7) << 3;
            #pragma unroll
            for (int m = 0; m < 8; ++m) {
                unsigned int w[4];
                #pragma unroll
                for (int pp = 0; pp < 4; ++pp) {
                    float v0 = u[tid * NBIT + m * 8 + 2 * pp];
                    float v1 = u[tid * NBIT + m * 8 + 2 * pp + 1];
                    w[pp] = pk2(v0, v1);
                }
                *reinterpret_cast<uint4*>(&Bt[ci * 64 + ((m * 8) ^ sw)]) = make_uint4(w[0], w[1], w[2], w[3]);
            }
        }
    }
    __syncthreads();

    // ---- A fragments: preconverted bf16(0.5*u), direct 16B loads ----
    const int wid  = tid >> 6;
    const int lane = tid & 63;
    const int lr   = lane & 15;
    const int g4   = lane >> 4;

    bf16x8 afrag[4][2];
    #pragma unroll
    for (int mt = 0; mt < 4; ++mt) {
        #pragma unroll
        for (int kb = 0; kb < 2; ++kb) {
            const int j = wid * 64 + mt * 16 + lr;
            union { bf16x8 v; uint4 q; } pk;
            pk.q = *reinterpret_cast<const uint4*>(&Abf[j * 64 + kb * 32 + g4 * 8]);
            afrag[mt][kb] = pk.v;
        }
    }
    int labR[4][4];
    #pragma unroll
    for (int mt = 0; mt < 4; ++mt)
        #pragma unroll
        for (int e = 0; e < 4; ++e)
            labR[mt][e] = labB[wid * 64 + mt * 16 + g4 * 4 + e];

    // ---- MFMA + fused softplus epilogue (ip pre-scaled by 0.5 via Abf) ----
    float sum2 = 0.f;
    for (int nt = 0; nt < 8; ++nt) {
        if (t0 + nt * 16 >= (long)T_TOTAL) break;   // block-uniform; 200000 % 16 == 0
        const int col = nt * 16 + lr;
        const int sw = (col & 7) << 3;
        union { bf16x8 v; uint4 q; } b0, b1;
        b0.q = *reinterpret_cast<const uint4*>(&Bt[col * 64 + ((g4 * 8) ^ sw)]);
        b1.q = *reinterpret_cast<const uint4*>(&Bt[col * 64 + ((32 + g4 * 8) ^ sw)]);
        const int labc = labT[col];
        #pragma unroll
        for (int mt = 0; mt < 4; ++mt) {
            f32x4 acc4 = {0.f, 0.f, 0.f, 0.f};
            acc4 = __builtin_amdgcn_mfma_f32_16x16x32_bf16(afrag[mt][0], b0.v, acc4, 0, 0, 0);
            acc4 = __builtin_amdgcn_mfma_f32_16x16x32_bf16(afrag[mt][1], b1.v, acc4, 0, 0, 0);
            #pragma unroll
            for (int e = 0; e < 4; ++e) {
                float ip = fminf(fmaxf(acc4[e], -100.f), 50.f);
                float z  = (labc == labR[mt][e]) ? -ip : ip;
                float tt = fmaf(z, LOG2E, LOG2E);    // (1+z)*log2(e), M = 1
                sum2 += hw_log2(1.f + hw_exp2(tt));  // * ln2 applied below
            }
        }
    }
    for (int off = 32; off; off >>= 1) sum2 += __shfl_xor(sum2, off);
    if (lane == 0) wpart[wid] = sum2;
    __syncthreads();
    if (tid == 0)
        partial[blockIdx.x] = (double)(wpart[0] + wpart[1] + wpart[2] + wpart[3]) * LN2;
}

// ---------------- kernel D: finalize loss ------------------------------------
__global__ __launch_bounds__(256) void fin_kernel(const double* __restrict__ partial,
                                                  const float* __restrict__ quant,
                                                  float* __restrict__ out0) {
    __shared__ double wp[4];
    double s = 0.0;
    for (int i = threadIdx.x; i < NBLK; i += 256) s += partial[i];
    for (int off = 32; off; off >>= 1) s += __shfl_xor(s, off);
    if ((threadIdx.x & 63) == 0) wp[threadIdx.x >> 6] = s;
    __syncthreads();
    if (threadIdx.x == 0) {
        double tot = wp[0] + wp[1] + wp[2] + wp[3];
        out0[0] = (float)(tot / ((double)BATCH * (double)T_TOTAL)
                          + 0.5 * ((double)quant[0] / (double)(BATCH * NBIT)));   // ETA=0.5
    }
}

extern "C" void kernel_launch(void* const* d_in, const int* in_sizes, int n_in,
                              void* d_out, int out_size, void* d_ws, size_t ws_size,
                              hipStream_t stream) {
    const float* u   = (const float*)d_in[0];
    const float* y   = (const float*)d_in[1];
    const int*   ind = (const int*)d_in[2];
    const float* U   = (const float*)d_in[3];
    const float* Y   = (const float*)d_in[4];
    const float* C   = (const float*)d_in[5];
    float* out = (float*)d_out;

    // ws layout (all write-before-read each call)
    float*          quant   = (float*)d_ws;                                   // 4 B
    int*            labB    = (int*)((char*)d_ws + 64);                       // 1 KB
    unsigned short* Abf     = (unsigned short*)((char*)d_ws + 2048);          // 32 KB
    double*         partial = (double*)((char*)d_ws + 36864);                 // 12.5 KB
    int*            lab_buf = (int*)((char*)d_ws + 65536);                    // 800 KB

    laby_prep_kernel<<<YBLK * NCLASS + 8, 256, 0, stream>>>(Y, lab_buf, u, y, labB, Abf);
    dcc_kernel<<<1, 256, 0, stream>>>(u, C, labB, out + 1, quant);
    metric_kernel<<<NBLK, 256, 0, stream>>>(u, U, ind, labB, lab_buf, Abf, partial);
    fin_kernel<<<1, 256, 0, stream>>>(partial, quant, out);
}